// Round 6
// baseline (427.240 us; speedup 1.0000x reference)
//
#include <hip/hip_runtime.h>

#define IN_F   8192
#define OUT_F  14336
#define M_TOK  64
#define ROWB   64                 // n-rows per block
#define NBLK   (OUT_F / ROWB)     // 224 blocks = 1 per CU (persistent tile)
#define SLABK  256                // k per slab -> 512 B of packed w per row
#define NSLAB  (IN_F / SLABK)     // 32
#define WROWB  512                // bytes per row per slab in LDS (no pad; read
                                  // conflicts hide under HBM-bound slab time)

typedef __attribute__((ext_vector_type(8))) short          bf16x8;
typedef __attribute__((ext_vector_type(8))) unsigned short u16x8;
typedef __attribute__((ext_vector_type(4))) float          f32x4;

__device__ __forceinline__ unsigned short f2bf_rne(float f) {
    unsigned u = __builtin_bit_cast(unsigned, f);
    u += 0x7FFFu + ((u >> 16) & 1u);
    return (unsigned short)(u >> 16);
}

// Prep: x fp32 -> A-fragment-swizzled bf16 in ws. 16-B unit (fg, mt, lane):
// element (m = mt*16 + (lane&15), k = fg*32 + (lane>>4)*8 + j). A gemm A-load
// of one fragment is then a single fully-coalesced 1-KB wave transaction.
__global__ __launch_bounds__(256) void qlin_prep(const float* __restrict__ x,
                                                 unsigned short* __restrict__ xs) {
    int tid  = blockIdx.x * 256 + threadIdx.x;      // 65536 total
    int lane = tid & 63;
    int mt   = (tid >> 6) & 3;
    int fg   = tid >> 8;                            // k-frag index 0..255
    int q = lane >> 4, t = lane & 15;
    const float* src = x + (size_t)(mt * 16 + t) * IN_F + fg * 32 + q * 8;
    u16x8 o;
#pragma unroll
    for (int j = 0; j < 8; ++j) o[j] = f2bf_rne(src[j]);
    *reinterpret_cast<u16x8*>(xs + (size_t)tid * 8) = o;
}

// One packed int32 (one byte: lo nibble = even k, hi nibble = odd k) -> two
// bf16 bit-patterns in one dword. Ints in [-8,7] are exact in bf16.
__device__ __forceinline__ int unpack2_bf16(int v) {
    int q0 = ((int)((unsigned)v << 28)) >> 28;
    int q1 = ((int)((unsigned)v << 24)) >> 28;
    unsigned u0 = __builtin_bit_cast(unsigned, (float)q0);
    unsigned u1 = __builtin_bit_cast(unsigned, (float)q1);
    return (int)((u0 >> 16) | (u1 & 0xFFFF0000u));
}

__device__ __forceinline__ bf16x8 unpack_b(int4 wv) {
    int4 pk;
    pk.x = unpack2_bf16(wv.x);
    pk.y = unpack2_bf16(wv.y);
    pk.z = unpack2_bf16(wv.z);
    pk.w = unpack2_bf16(wv.w);
    return __builtin_bit_cast(bf16x8, pk);
}

// Persistent-tile GEMM: block = 64 n x 64 m x full K, acc in registers.
// 32 slabs of 256 k; per slab stage 64 rows x 512-B CONTIGUOUS spans (the
// HBM-granule fix) into dbuf LDS (2 x 32 KB); waves split slab-K 4-ways
// (zero unpack/x redundancy); one barrier per slab; LDS k-reduce at end.
__global__ __launch_bounds__(256) void qlin_gemm(const unsigned short* __restrict__ xs,
                                                 const int* __restrict__ wp,
                                                 const float* __restrict__ scales,
                                                 const float* __restrict__ bias,
                                                 float* __restrict__ out) {
    __shared__ int wl[2][ROWB * WROWB / 4];   // 2 x 32 KB = 64 KB (reused by reduce)

    const int tid  = threadIdx.x;
    const int wave = tid >> 6;
    const int lane = tid & 63;
    const int t = lane & 15;      // A: m ; B: n ; C: col(n)
    const int q = lane >> 4;      // A/B: k = q*8+j ; C: row base q*4
    const int n0 = blockIdx.x * ROWB;

    const char* wpb = (const char*)wp;
    // staging addressing: instr j covers rows 2*(wave*8+j) + (lane>>5)
    const int srow = 2 * wave * 8 + (lane >> 5);   // + 2*j in loop
    const int scol = (lane & 31) * 16;             // byte within 512-B span

    f32x4 acc[4][4] = {};   // [nt][mt]

    int4 g[8];
    // ---- prologue: slab 0 ----
#pragma unroll
    for (int j = 0; j < 8; ++j)
        g[j] = *reinterpret_cast<const int4*>(
            wpb + (size_t)(n0 + srow + 2 * j) * 16384 + scol);
#pragma unroll
    for (int j = 0; j < 8; ++j)
        *reinterpret_cast<int4*>((char*)wl[0] + (srow + 2 * j) * WROWB + scol) = g[j];
    __syncthreads();

    for (int s = 0; s < NSLAB; ++s) {
        const int buf = s & 1;
        // ---- prefetch slab s+1 into registers (in flight during compute) ----
        if (s + 1 < NSLAB) {
#pragma unroll
            for (int j = 0; j < 8; ++j)
                g[j] = *reinterpret_cast<const int4*>(
                    wpb + (size_t)(n0 + srow + 2 * j) * 16384 + (size_t)(s + 1) * WROWB + scol);
        }
        // ---- compute slab s: wave's k-subrange = slab + wave*64 .. +64 ----
#pragma unroll
        for (int f = 0; f < 2; ++f) {
            bf16x8 a[4];
            const int fg = s * 8 + wave * 2 + f;   // global k-frag index
#pragma unroll
            for (int mt = 0; mt < 4; ++mt)
                a[mt] = *reinterpret_cast<const bf16x8*>(
                    xs + ((size_t)(fg * 4 + mt) * 64 + lane) * 8);
#pragma unroll
            for (int nt = 0; nt < 4; ++nt) {
                int4 wv = *reinterpret_cast<const int4*>(
                    (const char*)wl[buf] + (nt * 16 + t) * WROWB + wave * 128 + f * 64 + q * 16);
                bf16x8 b = unpack_b(wv);
#pragma unroll
                for (int mt = 0; mt < 4; ++mt)
                    acc[nt][mt] = __builtin_amdgcn_mfma_f32_16x16x32_bf16(
                        a[mt], b, acc[nt][mt], 0, 0, 0);
            }
        }
        // ---- park slab s+1 into the other LDS buffer ----
        if (s + 1 < NSLAB) {
#pragma unroll
            for (int j = 0; j < 8; ++j)
                *reinterpret_cast<int4*>(
                    (char*)wl[buf ^ 1] + (srow + 2 * j) * WROWB + scol) = g[j];
        }
        __syncthreads();
    }

    // ---- cross-wave k-reduce through LDS (reuse wl = 64 KB = 4x64x64 fp32) ----
    float* red = (float*)wl;
#pragma unroll
    for (int nt = 0; nt < 4; ++nt)
#pragma unroll
        for (int mt = 0; mt < 4; ++mt)
#pragma unroll
            for (int r = 0; r < 4; ++r)
                red[wave * 4096 + (nt * 16 + t) * 64 + mt * 16 + q * 4 + r] =
                    acc[nt][mt][r];
    __syncthreads();

    const int m  = tid >> 2;          // 0..63
    const int ng = (tid & 3) * 16;    // n start within tile
#pragma unroll
    for (int i = 0; i < 16; i += 4) {
        float4 v;
#pragma unroll
        for (int c = 0; c < 4; ++c) {
            const int nl = ng + i + c;
            float sum = red[0 * 4096 + nl * 64 + m] + red[1 * 4096 + nl * 64 + m]
                      + red[2 * 4096 + nl * 64 + m] + red[3 * 4096 + nl * 64 + m];
            v[c] = sum * scales[n0 + nl] + bias[n0 + nl];
        }
        *reinterpret_cast<float4*>(out + (size_t)m * OUT_F + n0 + ng + i) = v;
    }
}

extern "C" void kernel_launch(void* const* d_in, const int* in_sizes, int n_in,
                              void* d_out, int out_size, void* d_ws, size_t ws_size,
                              hipStream_t stream) {
    const float* x    = (const float*)d_in[0];
    const int*   wp   = (const int*)d_in[1];
    const float* sc   = (const float*)d_in[2];
    const float* bias = (const float*)d_in[3];
    float* out = (float*)d_out;
    unsigned short* xs = (unsigned short*)d_ws;   // 1 MB swizzled bf16 x

    qlin_prep<<<256, 256, 0, stream>>>(x, xs);
    qlin_gemm<<<NBLK, 256, 0, stream>>>(xs, wp, sc, bias, out);
}

// Round 7
// 405.614 us; speedup vs baseline: 1.0533x; 1.0533x over previous
//
#include <hip/hip_runtime.h>

#define IN_F   8192
#define OUT_F  14336
#define M_TOK  64
#define KPI    4096               // int32 per weight row
#define BN     64                 // n per block (4 waves x 16)
#define NBLK   (OUT_F / BN)       // 224
#define KSPLIT 8
#define GPERK  8                  // 128-k groups per k-split chunk (8*128=1024 k)
#define NG     64                 // 128-k groups per row total (8192/128)
#define PSTR   (M_TOK * OUT_F)    // floats per partial

typedef __attribute__((ext_vector_type(8))) short          bf16x8;
typedef __attribute__((ext_vector_type(8))) unsigned short u16x8;
typedef __attribute__((ext_vector_type(4))) float          f32x4;

__device__ __forceinline__ unsigned short f2bf_rne(float f) {
    unsigned u = __builtin_bit_cast(unsigned, f);
    u += 0x7FFFu + ((u >> 16) & 1u);
    return (unsigned short)(u >> 16);
}

// x fp32 -> A-fragment-swizzled bf16 (verified in R6): 16-B unit (fg, mt, lane)
// holds x[m = mt*16 + (lane&15)][k = fg*32 + (lane>>4)*8 + j].
__global__ __launch_bounds__(256) void qlin_prep(const float* __restrict__ x,
                                                 unsigned short* __restrict__ xs) {
    int tid  = blockIdx.x * 256 + threadIdx.x;      // 65536
    int lane = tid & 63;
    int mt   = (tid >> 6) & 3;
    int fg   = tid >> 8;
    int q = lane >> 4, t = lane & 15;
    const float* src = x + (size_t)(mt * 16 + t) * IN_F + fg * 32 + q * 8;
    u16x8 o;
#pragma unroll
    for (int j = 0; j < 8; ++j) o[j] = f2bf_rne(src[j]);
    *reinterpret_cast<u16x8*>(xs + (size_t)tid * 8) = o;
}

// Compact 235 MB int32-boxed bytes -> 59 MB fragment-ordered byte stream.
// Thread: 4 consecutive int32 of row n (16-B coalesced read) -> one dword
// (4 payload bytes) at dst ((G*64+g)*64 + q*16 + t)*4 + i  where
// G=n/16, t=n%16, pg=tid%1024, g=pg>>4, i=(pg&15)>>2, q=pg&3.
// GEMM lane (t,q) then reads dwordx4 = frags F=g*4+0..3, pairs F*16+q*4..+4.
__global__ __launch_bounds__(256) void qlin_repack(const int* __restrict__ wp,
                                                   unsigned* __restrict__ rep) {
    int tid = blockIdx.x * 256 + threadIdx.x;       // 14,680,064
    int n   = tid >> 10;
    int pg  = tid & 1023;
    int4 v = *reinterpret_cast<const int4*>(wp + (size_t)n * KPI + pg * 4);
    unsigned d = (unsigned)(v.x & 255) | ((unsigned)(v.y & 255) << 8)
               | ((unsigned)(v.z & 255) << 16) | ((unsigned)(v.w & 255) << 24);
    int G = n >> 4, t = n & 15;
    int g = pg >> 4, i = (pg & 15) >> 2, q = pg & 3;
    rep[(((size_t)(G * 64 + g) * 64) + q * 16 + t) * 4 + i] = d;
}

// One payload byte (lo nibble = even k, hi nibble = odd k) -> two bf16
// bit-patterns in one dword (ints [-8,7] exact in bf16).
__device__ __forceinline__ int unpack2_bf16(int v) {
    int q0 = ((int)((unsigned)v << 28)) >> 28;
    int q1 = ((int)((unsigned)v << 24)) >> 28;
    unsigned u0 = __builtin_bit_cast(unsigned, (float)q0);
    unsigned u1 = __builtin_bit_cast(unsigned, (float)q1);
    return (int)((u0 >> 16) | (u1 & 0xFFFF0000u));
}

// One dword of the rep stream = one B-fragment (4 bytes -> 8 bf16).
__device__ __forceinline__ bf16x8 unpack_frag(unsigned d) {
    int4 pk;
    pk.x = unpack2_bf16((int)(d));
    pk.y = unpack2_bf16((int)(d >> 8));
    pk.z = unpack2_bf16((int)(d >> 16));
    pk.w = unpack2_bf16((int)(d >> 24));
    return __builtin_bit_cast(bf16x8, pk);
}

// Barrier-free streaming GEMM: no LDS. Wave owns n = n0 + wave*16 + t.
// Per 128-k group: 1 coalesced dwordx4 w-load (1 KB/wave) + 16 coalesced
// a-loads (xs, L2-hot) + unpack + 16 MFMA. KSPLIT=8 -> 1792 blocks
// (~20+ waves/CU), partials to ws (reduced by qlin_reduce).
__global__ __launch_bounds__(256) void qlin_gemm(const unsigned short* __restrict__ xs,
                                                 const unsigned* __restrict__ rep,
                                                 const float* __restrict__ scales,
                                                 float* __restrict__ part) {
    const int tid  = threadIdx.x;
    const int wave = tid >> 6;
    const int lane = tid & 63;
    const int t = lane & 15;      // A: m ; B: n ; C/D: col
    const int q = lane >> 4;      // A/B: k sub ; C/D: row base q*4

    const int nblk = blockIdx.x % NBLK;
    const int kblk = blockIdx.x / NBLK;
    const int G    = nblk * 4 + wave;          // n-group of 16
    const int n    = G * 16 + t;

    // w stream: group g -> dwords ((G*64+g)*64 + q*16 + t)*4 .. +3
    const unsigned* wbase = rep + (((size_t)(G * 64 + kblk * GPERK) * 64) + q * 16 + t) * 4;

    f32x4 acc[4] = {};   // mt = 0..3 (m = mt*16 + q*4 + r rows via C/D layout)

#pragma unroll
    for (int gi = 0; gi < GPERK; ++gi) {
        uint4 wd = *reinterpret_cast<const uint4*>(wbase + (size_t)gi * 256);
#pragma unroll
        for (int i = 0; i < 4; ++i) {
            const unsigned d = (i == 0) ? wd.x : (i == 1) ? wd.y : (i == 2) ? wd.z : wd.w;
            bf16x8 b = unpack_frag(d);
            const int F = (kblk * GPERK + gi) * 4 + i;   // 32-k frag index
#pragma unroll
            for (int mt = 0; mt < 4; ++mt) {
                bf16x8 a = *reinterpret_cast<const bf16x8*>(
                    xs + ((size_t)(F * 4 + mt) * 64 + lane) * 8);
                acc[mt] = __builtin_amdgcn_mfma_f32_16x16x32_bf16(a, b, acc[mt], 0, 0, 0);
            }
        }
    }

    const float sc = scales[n];
    float* p = part + (size_t)kblk * PSTR;
#pragma unroll
    for (int mt = 0; mt < 4; ++mt)
#pragma unroll
        for (int r = 0; r < 4; ++r)
            p[(size_t)(mt * 16 + q * 4 + r) * OUT_F + n] = acc[mt][r] * sc;
}

// out = bias + sum of KSPLIT partials. 229376 float4 threads.
__global__ __launch_bounds__(256) void qlin_reduce(const float* __restrict__ part,
                                                   const float* __restrict__ bias,
                                                   float* __restrict__ out) {
    int g = blockIdx.x * 256 + threadIdx.x;
    float4 acc = reinterpret_cast<const float4*>(bias)[g % (OUT_F / 4)];
#pragma unroll
    for (int s = 0; s < KSPLIT; ++s) {
        float4 v = reinterpret_cast<const float4*>(part + (size_t)s * PSTR)[g];
        acc.x += v.x; acc.y += v.y; acc.z += v.z; acc.w += v.w;
    }
    reinterpret_cast<float4*>(out)[g] = acc;
}

extern "C" void kernel_launch(void* const* d_in, const int* in_sizes, int n_in,
                              void* d_out, int out_size, void* d_ws, size_t ws_size,
                              hipStream_t stream) {
    const float* x    = (const float*)d_in[0];
    const int*   wp   = (const int*)d_in[1];
    const float* sc   = (const float*)d_in[2];
    const float* bias = (const float*)d_in[3];
    float* out = (float*)d_out;

    unsigned short* xs   = (unsigned short*)d_ws;                    // 1 MB
    unsigned*       rp   = (unsigned*)((char*)d_ws + (1 << 20));     // 59 MB (56 MiB)
    float*          part = (float*)((char*)d_ws + (64u << 20));      // 8 x 3.67 MB

    qlin_prep<<<256, 256, 0, stream>>>(x, xs);
    qlin_repack<<<(OUT_F * (KPI / 4)) / 256, 256, 0, stream>>>(wp, rp);
    qlin_gemm<<<NBLK * KSPLIT, 256, 0, stream>>>(xs, rp, sc, part);
    qlin_reduce<<<(M_TOK * OUT_F) / 4 / 256, 256, 0, stream>>>(part, bias, out);
}

// Round 8
// 370.652 us; speedup vs baseline: 1.1527x; 1.0943x over previous
//
#include <hip/hip_runtime.h>

#define IN_F   8192
#define OUT_F  14336
#define M_TOK  64
#define KPI    4096               // int32 per weight row
#define NBLK   448                // n-blocks (32 n each)
#define KSPLIT 4
#define PSTR   (M_TOK * OUT_F)    // floats per k-partial

typedef __attribute__((ext_vector_type(8))) short          bf16x8;
typedef __attribute__((ext_vector_type(8))) unsigned short u16x8;
typedef __attribute__((ext_vector_type(4))) float          f32x4;

__device__ __forceinline__ unsigned short f2bf_rne(float f) {
    unsigned u = __builtin_bit_cast(unsigned, f);
    u += 0x7FFFu + ((u >> 16) & 1u);
    return (unsigned short)(u >> 16);
}

// x fp32 -> A-fragment-swizzled bf16 (R6/R7-verified): 16-B unit (F, mt, lane)
// holds x[m = mt*16 + (lane&15)][k = F*32 + (lane>>4)*8 + j].
__global__ __launch_bounds__(256) void qlin_prep(const float* __restrict__ x,
                                                 unsigned short* __restrict__ xs) {
    int tid  = blockIdx.x * 256 + threadIdx.x;      // 65536
    int lane = tid & 63;
    int mt   = (tid >> 6) & 3;
    int fg   = tid >> 8;
    int q = lane >> 4, t = lane & 15;
    const float* src = x + (size_t)(mt * 16 + t) * IN_F + fg * 32 + q * 8;
    u16x8 o;
#pragma unroll
    for (int j = 0; j < 8; ++j) o[j] = f2bf_rne(src[j]);
    *reinterpret_cast<u16x8*>(xs + (size_t)tid * 8) = o;
}

// Repack v2: same rep layout as R7 (gemm-verified), but transposed through LDS
// so BOTH global sides are coalesced (R7's repack scatter-stored 64 lines/wave).
// rep dword ((G*64+g)*64 + q*16 + t)*4 + i, byte c = payload(wp[n*KPI + 64g+16i+4q+c]),
// n = G*16+t. Block = (G, g8): 8 rounds coalesced int4 row-reads -> LDS slab ->
// barrier -> 2 coalesced dwordx4 stores into the block's CONTIGUOUS 8-KB rep region.
__global__ __launch_bounds__(256) void qlin_repack(const int* __restrict__ wp,
                                                   unsigned* __restrict__ rep) {
    __shared__ unsigned lds[2048];                  // 8 KB
    const int G   = blockIdx.x >> 3;                // 0..895
    const int g8  = blockIdx.x & 7;
    const int tid = threadIdx.x;
    const int r = tid >> 4, T = tid & 15;           // row-in-group, chunk
    const int q = T & 3, i = T >> 2;
    const int* src = wp + (size_t)(G * 16 + r) * KPI + T * 4;
#pragma unroll
    for (int j = 0; j < 8; ++j) {
        const int g = g8 * 8 + j;
        int4 v = *reinterpret_cast<const int4*>(src + 64 * g);
        unsigned d = (unsigned)(v.x & 255) | ((unsigned)(v.y & 255) << 8)
                   | ((unsigned)(v.z & 255) << 16) | ((unsigned)(v.w & 255) << 24);
        lds[j * 256 + q * 64 + r * 4 + i] = d;
    }
    __syncthreads();
    unsigned* dst = rep + ((size_t)G * 64 + g8 * 8) * 256;
#pragma unroll
    for (int s = 0; s < 2; ++s)
        *reinterpret_cast<uint4*>(dst + s * 1024 + tid * 4) =
            *reinterpret_cast<const uint4*>(&lds[s * 1024 + tid * 4]);
}

// payload byte (lo nibble = even k, hi nibble = odd k) -> two bf16 bit-patterns.
__device__ __forceinline__ int unpack2_bf16(int v) {
    int q0 = ((int)((unsigned)v << 28)) >> 28;
    int q1 = ((int)((unsigned)v << 24)) >> 28;
    unsigned u0 = __builtin_bit_cast(unsigned, (float)q0);
    unsigned u1 = __builtin_bit_cast(unsigned, (float)q1);
    return (int)((u0 >> 16) | (u1 & 0xFFFF0000u));
}

__device__ __forceinline__ bf16x8 unpack_frag(unsigned d) {
    int4 pk;
    pk.x = unpack2_bf16((int)(d));
    pk.y = unpack2_bf16((int)(d >> 8));
    pk.z = unpack2_bf16((int)(d >> 16));
    pk.w = unpack2_bf16((int)(d >> 24));
    return __builtin_bit_cast(bf16x8, pk);
}

// Barrier-free streaming GEMM (R7 family, n-doubled): block = 32 n x 64 m x
// k-chunk 2048; wave w takes k-sub [w*512,(w+1)*512) for BOTH 16-n groups
// (halves x traffic vs R7). Sequential 8-KB w-stream per wave per group.
// Epilogue: LDS cross-wave k-reduce -> RAW partial sums (scale applied in reduce).
__global__ __launch_bounds__(256, 4) void qlin_gemm(const unsigned short* __restrict__ xs,
                                                    const unsigned* __restrict__ rep,
                                                    float* __restrict__ part) {
    __shared__ float red[4 * 2048];                 // 32 KB
    const int tid  = threadIdx.x;
    const int wave = tid >> 6;
    const int lane = tid & 63;
    const int t = lane & 15;      // A: m ; B: n ; C/D: col
    const int q = lane >> 4;      // A/B: k-sub ; C/D: row base q*4

    const int nb   = blockIdx.x % NBLK;
    const int kblk = blockIdx.x / NBLK;
    const int g0   = kblk * 16 + wave * 4;          // first 128-k group

    const unsigned* b0p = rep + ((size_t)((nb * 2)     * 64 + g0) * 64 + q * 16 + t) * 4;
    const unsigned* b1p = rep + ((size_t)((nb * 2 + 1) * 64 + g0) * 64 + q * 16 + t) * 4;

    f32x4 acc[2][4] = {};   // [ng][mt]

#pragma unroll
    for (int gi = 0; gi < 4; ++gi) {
        uint4 w0 = *reinterpret_cast<const uint4*>(b0p + (size_t)gi * 256);
        uint4 w1 = *reinterpret_cast<const uint4*>(b1p + (size_t)gi * 256);
        const unsigned* d0 = reinterpret_cast<const unsigned*>(&w0);
        const unsigned* d1 = reinterpret_cast<const unsigned*>(&w1);
#pragma unroll
        for (int i = 0; i < 4; ++i) {
            bf16x8 b0 = unpack_frag(d0[i]);
            bf16x8 b1 = unpack_frag(d1[i]);
            const int F = (g0 + gi) * 4 + i;        // 32-k frag index
#pragma unroll
            for (int mt = 0; mt < 4; ++mt) {
                bf16x8 a = *reinterpret_cast<const bf16x8*>(
                    xs + ((size_t)(F * 4 + mt) * 64 + lane) * 8);
                acc[0][mt] = __builtin_amdgcn_mfma_f32_16x16x32_bf16(a, b0, acc[0][mt], 0, 0, 0);
                acc[1][mt] = __builtin_amdgcn_mfma_f32_16x16x32_bf16(a, b1, acc[1][mt], 0, 0, 0);
            }
        }
    }

    // ---- cross-wave k-reduce: red[wave][m*32 + nl], m=mt*16+q*4+r, nl=ng*16+t ----
#pragma unroll
    for (int ng = 0; ng < 2; ++ng)
#pragma unroll
        for (int mt = 0; mt < 4; ++mt)
#pragma unroll
            for (int r = 0; r < 4; ++r)
                red[wave * 2048 + (mt * 16 + q * 4 + r) * 32 + ng * 16 + t] = acc[ng][mt][r];
    __syncthreads();

    const int m  = tid >> 2;
    const int nq = tid & 3;
    float* p = part + (size_t)kblk * PSTR + (size_t)m * OUT_F + nb * 32 + nq * 8;
    float4 v0, v1;
#pragma unroll
    for (int e = 0; e < 4; ++e) {
        const int a0 = m * 32 + nq * 8 + e;
        const int a1 = a0 + 4;
        v0[e] = red[a0] + red[2048 + a0] + red[4096 + a0] + red[6144 + a0];
        v1[e] = red[a1] + red[2048 + a1] + red[4096 + a1] + red[6144 + a1];
    }
    *reinterpret_cast<float4*>(p)     = v0;
    *reinterpret_cast<float4*>(p + 4) = v1;
}

// out = (sum of 4 raw partials) * scale[n] + bias[n]. 229376 float4 threads.
__global__ __launch_bounds__(256) void qlin_reduce(const float* __restrict__ part,
                                                   const float* __restrict__ scales,
                                                   const float* __restrict__ bias,
                                                   float* __restrict__ out) {
    int g  = blockIdx.x * 256 + threadIdx.x;        // 0..229375
    int n4 = g % (OUT_F / 4);
    float4 s4 = reinterpret_cast<const float4*>(scales)[n4];
    float4 b4 = reinterpret_cast<const float4*>(bias)[n4];
    float4 a = {0.f, 0.f, 0.f, 0.f};
#pragma unroll
    for (int s = 0; s < KSPLIT; ++s) {
        float4 v = reinterpret_cast<const float4*>(part)[(size_t)s * (PSTR / 4) + g];
        a.x += v.x; a.y += v.y; a.z += v.z; a.w += v.w;
    }
    float4 o;
    o.x = a.x * s4.x + b4.x;
    o.y = a.y * s4.y + b4.y;
    o.z = a.z * s4.z + b4.z;
    o.w = a.w * s4.w + b4.w;
    reinterpret_cast<float4*>(out)[g] = o;
}

extern "C" void kernel_launch(void* const* d_in, const int* in_sizes, int n_in,
                              void* d_out, int out_size, void* d_ws, size_t ws_size,
                              hipStream_t stream) {
    const float* x    = (const float*)d_in[0];
    const int*   wp   = (const int*)d_in[1];
    const float* sc   = (const float*)d_in[2];
    const float* bias = (const float*)d_in[3];
    float* out = (float*)d_out;

    unsigned short* xs   = (unsigned short*)d_ws;                    // 1 MiB
    unsigned*       rp   = (unsigned*)((char*)d_ws + (1 << 20));     // 56 MiB
    float*          part = (float*)((char*)d_ws + (64u << 20));      // 4 x 3.5 MiB

    qlin_prep<<<256, 256, 0, stream>>>(x, xs);
    qlin_repack<<<896 * 8, 256, 0, stream>>>(wp, rp);
    qlin_gemm<<<NBLK * KSPLIT, 256, 0, stream>>>(xs, rp, part);
    qlin_reduce<<<(M_TOK * OUT_F) / 4 / 256, 256, 0, stream>>>(part, sc, bias, out);
}

// Round 9
// 368.309 us; speedup vs baseline: 1.1600x; 1.0064x over previous
//
#include <hip/hip_runtime.h>

#define IN_F   8192
#define OUT_F  14336
#define M_TOK  64
#define KPI    4096               // int32 per weight row
#define NBLK   112                // n-blocks (128 n each)
#define KSPLIT 4
#define PSTR   (M_TOK * OUT_F)    // floats per k-partial

typedef __attribute__((ext_vector_type(8))) short          bf16x8;
typedef __attribute__((ext_vector_type(8))) unsigned short u16x8;
typedef __attribute__((ext_vector_type(4))) float          f32x4;

__device__ __forceinline__ unsigned short f2bf_rne(float f) {
    unsigned u = __builtin_bit_cast(unsigned, f);
    u += 0x7FFFu + ((u >> 16) & 1u);
    return (unsigned short)(u >> 16);
}

// x fp32 -> A-fragment-swizzled bf16 (R6-R8-verified): 16-B unit (F, mt, lane)
// holds x[m = mt*16 + (lane&15)][k = F*32 + (lane>>4)*8 + j].
__global__ __launch_bounds__(256) void qlin_prep(const float* __restrict__ x,
                                                 unsigned short* __restrict__ xs) {
    int tid  = blockIdx.x * 256 + threadIdx.x;      // 65536
    int lane = tid & 63;
    int mt   = (tid >> 6) & 3;
    int fg   = tid >> 8;
    int q = lane >> 4, t = lane & 15;
    const float* src = x + (size_t)(mt * 16 + t) * IN_F + fg * 32 + q * 8;
    u16x8 o;
#pragma unroll
    for (int j = 0; j < 8; ++j) o[j] = f2bf_rne(src[j]);
    *reinterpret_cast<u16x8*>(xs + (size_t)tid * 8) = o;
}

// Repack (R8-verified, both sides coalesced, at streaming roofline):
// rep dword ((G*64+g)*64 + q*16 + t)*4 + i holds payload bytes of
// wp[(G*16+t)*KPI + 64g + 16i + 4q + 0..3].
__global__ __launch_bounds__(256) void qlin_repack(const int* __restrict__ wp,
                                                   unsigned* __restrict__ rep) {
    __shared__ unsigned lds[2048];                  // 8 KB
    const int G   = blockIdx.x >> 3;                // 0..895
    const int g8  = blockIdx.x & 7;
    const int tid = threadIdx.x;
    const int r = tid >> 4, T = tid & 15;
    const int q = T & 3, i = T >> 2;
    const int* src = wp + (size_t)(G * 16 + r) * KPI + T * 4;
#pragma unroll
    for (int j = 0; j < 8; ++j) {
        const int g = g8 * 8 + j;
        int4 v = *reinterpret_cast<const int4*>(src + 64 * g);
        unsigned d = (unsigned)(v.x & 255) | ((unsigned)(v.y & 255) << 8)
                   | ((unsigned)(v.z & 255) << 16) | ((unsigned)(v.w & 255) << 24);
        lds[j * 256 + q * 64 + r * 4 + i] = d;
    }
    __syncthreads();
    unsigned* dst = rep + ((size_t)G * 64 + g8 * 8) * 256;
#pragma unroll
    for (int s = 0; s < 2; ++s)
        *reinterpret_cast<uint4*>(dst + s * 1024 + tid * 4) =
            *reinterpret_cast<const uint4*>(&lds[s * 1024 + tid * 4]);
}

// payload byte (lo nibble = even k, hi nibble = odd k) -> two bf16 bit-patterns.
__device__ __forceinline__ int unpack2_bf16(int v) {
    int q0 = ((int)((unsigned)v << 28)) >> 28;
    int q1 = ((int)((unsigned)v << 24)) >> 28;
    unsigned u0 = __builtin_bit_cast(unsigned, (float)q0);
    unsigned u1 = __builtin_bit_cast(unsigned, (float)q1);
    return (int)((u0 >> 16) | (u1 & 0xFFFF0000u));
}

__device__ __forceinline__ bf16x8 unpack_frag(unsigned d) {
    int4 pk;
    pk.x = unpack2_bf16((int)(d));
    pk.y = unpack2_bf16((int)(d >> 8));
    pk.z = unpack2_bf16((int)(d >> 16));
    pk.w = unpack2_bf16((int)(d >> 24));
    return __builtin_bit_cast(bf16x8, pk);
}

// GEMM v3: block = 128 n x 64 m x 2048 k; wave takes 512 k for ALL 128 n
// (4x the A-reuse of R8 -> x traffic 448->115 MB; TA-bound floor ~28 us).
// Per 128-k sub-chunk: 16 A-frags pinned in regs, stream 8 n-groups of w.
// acc[8][4] = 128 VGPR; launch_bounds(256,2) caps at 256 VGPR, 2 waves/SIMD.
// Epilogue: 2-round (m-halves) 64-KB LDS cross-wave k-reduce -> raw partials.
__global__ __launch_bounds__(256, 2) void qlin_gemm(const unsigned short* __restrict__ xs,
                                                    const unsigned* __restrict__ rep,
                                                    float* __restrict__ part) {
    __shared__ float red[4 * 128 * 32];             // 64 KB
    const int tid  = threadIdx.x;
    const int wave = tid >> 6;
    const int lane = tid & 63;
    const int t = lane & 15;      // A: m ; B: n ; C/D: col
    const int q = lane >> 4;      // A/B: k-sub ; C/D: row base q*4

    const int nb   = blockIdx.x % NBLK;
    const int kblk = blockIdx.x / NBLK;
    const int g0   = kblk * 16 + wave * 4;          // wave's first 128-k group

    // w stream base: dword ((G*64+g)*64 + lane)*4, G = nb*8+ng, g = g0+sub
    const unsigned* wbase = rep + ((size_t)(nb * 8 * 64 + g0) * 64 + lane) * 4;

    f32x4 acc[8][4] = {};   // [ng][mt]

#pragma unroll
    for (int sub = 0; sub < 4; ++sub) {
        const int g = g0 + sub;
        bf16x8 a[4][4];                             // [i][mt] : 64 VGPR
#pragma unroll
        for (int i = 0; i < 4; ++i)
#pragma unroll
            for (int mt = 0; mt < 4; ++mt)
                a[i][mt] = *reinterpret_cast<const bf16x8*>(
                    xs + ((size_t)((g * 4 + i) * 4 + mt) * 64 + lane) * 8);
#pragma unroll
        for (int ng = 0; ng < 8; ++ng) {
            uint4 wd = *reinterpret_cast<const uint4*>(
                wbase + (size_t)ng * 16384 + sub * 256);
            const unsigned* d = reinterpret_cast<const unsigned*>(&wd);
#pragma unroll
            for (int i = 0; i < 4; ++i) {
                bf16x8 b = unpack_frag(d[i]);
#pragma unroll
                for (int mt = 0; mt < 4; ++mt)
                    acc[ng][mt] = __builtin_amdgcn_mfma_f32_16x16x32_bf16(
                        a[i][mt], b, acc[ng][mt], 0, 0, 0);
            }
        }
    }

    // ---- epilogue: two m-halves through 64-KB LDS ----
#pragma unroll
    for (int h = 0; h < 2; ++h) {
        if (h) __syncthreads();                     // previous round's reads done
#pragma unroll
        for (int ng = 0; ng < 8; ++ng)
#pragma unroll
            for (int mi = 0; mi < 2; ++mi)          // mt = h*2 + mi
#pragma unroll
                for (int r = 0; r < 4; ++r)
                    red[wave * 4096 + (ng * 16 + t) * 32 + mi * 16 + q * 4 + r] =
                        acc[ng][h * 2 + mi][r];
        __syncthreads();

        const int ml = tid >> 3;                    // 0..31 (m within half)
        const int nq = tid & 7;
        float* p = part + (size_t)kblk * PSTR
                 + (size_t)(h * 32 + ml) * OUT_F + nb * 128;
#pragma unroll
        for (int j = 0; j < 4; ++j) {
            const int nf = nq + j * 8;              // float4 index 0..31
            float4 v;
#pragma unroll
            for (int e = 0; e < 4; ++e) {
                const int nl = nf * 4 + e;
                v[e] = red[0 * 4096 + nl * 32 + ml] + red[1 * 4096 + nl * 32 + ml]
                     + red[2 * 4096 + nl * 32 + ml] + red[3 * 4096 + nl * 32 + ml];
            }
            *reinterpret_cast<float4*>(p + nf * 4) = v;
        }
    }
}

// out = (sum of 4 raw partials) * scale[n] + bias[n]. 229376 float4 threads.
__global__ __launch_bounds__(256) void qlin_reduce(const float* __restrict__ part,
                                                   const float* __restrict__ scales,
                                                   const float* __restrict__ bias,
                                                   float* __restrict__ out) {
    int g  = blockIdx.x * 256 + threadIdx.x;        // 0..229375
    int n4 = g % (OUT_F / 4);
    float4 s4 = reinterpret_cast<const float4*>(scales)[n4];
    float4 b4 = reinterpret_cast<const float4*>(bias)[n4];
    float4 a = {0.f, 0.f, 0.f, 0.f};
#pragma unroll
    for (int s = 0; s < KSPLIT; ++s) {
        float4 v = reinterpret_cast<const float4*>(part)[(size_t)s * (PSTR / 4) + g];
        a.x += v.x; a.y += v.y; a.z += v.z; a.w += v.w;
    }
    float4 o;
    o.x = a.x * s4.x + b4.x;
    o.y = a.y * s4.y + b4.y;
    o.z = a.z * s4.z + b4.z;
    o.w = a.w * s4.w + b4.w;
    reinterpret_cast<float4*>(out)[g] = o;
}

extern "C" void kernel_launch(void* const* d_in, const int* in_sizes, int n_in,
                              void* d_out, int out_size, void* d_ws, size_t ws_size,
                              hipStream_t stream) {
    const float* x    = (const float*)d_in[0];
    const int*   wp   = (const int*)d_in[1];
    const float* sc   = (const float*)d_in[2];
    const float* bias = (const float*)d_in[3];
    float* out = (float*)d_out;

    unsigned short* xs   = (unsigned short*)d_ws;                    // 1 MiB
    unsigned*       rp   = (unsigned*)((char*)d_ws + (1 << 20));     // 56 MiB
    float*          part = (float*)((char*)d_ws + (64u << 20));      // 4 x 3.5 MiB

    qlin_prep<<<256, 256, 0, stream>>>(x, xs);
    qlin_repack<<<896 * 8, 256, 0, stream>>>(wp, rp);
    qlin_gemm<<<NBLK * KSPLIT, 256, 0, stream>>>(xs, rp, part);
    qlin_reduce<<<(M_TOK * OUT_F) / 4 / 256, 256, 0, stream>>>(part, sc, bias, out);
}